// Round 1
// 238.516 us; speedup vs baseline: 1.0926x; 1.0926x over previous
//
#include <hip/hip_runtime.h>
#include <math.h>
#include <stdint.h>

#define HIDDEN 640
#define NTOK   16384   // 32*512
#define LSEQ   512
#define BATCH  32
#define NQH    10
#define NKVH   2
#define HDIM   64
#define GROUPS 5

typedef int      int4v  __attribute__((ext_vector_type(4)));
typedef int      int16v __attribute__((ext_vector_type(16)));
typedef _Float16 f16x8  __attribute__((ext_vector_type(8)));
typedef _Float16 f16x2  __attribute__((ext_vector_type(2)));
typedef float    f32x4  __attribute__((ext_vector_type(4)));

// ---------------------------------------------------------------------------
__device__ __forceinline__ float wred_sum(float v){
  #pragma unroll
  for (int m=1;m<64;m<<=1) v += __shfl_xor(v,m);
  return v;
}
__device__ __forceinline__ float wred_max(float v){
  #pragma unroll
  for (int m=1;m<64;m<<=1) v = fmaxf(v,__shfl_xor(v,m));
  return v;
}

// fragment-layout flat address for an MxK i8 matrix (K=640), used for both
// A (m rows) and B (n rows): lane-linear 16B per (32-row, 32-k) block.
__device__ __forceinline__ int frag_flat(int m, int k){
  return (((m>>5)*20 + (k>>5))<<10) + (((((k>>4)&1)<<5) | (m&31))<<4) + (k&15);
}

// ---------------------------------------------------------------------------
__global__ __launch_bounds__(256) void absum4_kernel(
    const float* __restrict__ w0, const float* __restrict__ w1,
    const float* __restrict__ w2, const float* __restrict__ w3,
    float* __restrict__ sums){
  const float* w; int n;
  switch(blockIdx.y){
    case 0:  w=w0; n=640*640; break;
    case 1:  w=w1; n=128*640; break;
    case 2:  w=w2; n=128*640; break;
    default: w=w3; n=640*640; break;
  }
  __shared__ float red[256];
  int tid = threadIdx.x;
  float s = 0.f;
  for (int i = blockIdx.x*256 + tid; i < n; i += gridDim.x*256) s += fabsf(w[i]);
  red[tid] = s; __syncthreads();
  for (int off=128; off>0; off>>=1){ if (tid<off) red[tid]+=red[tid+off]; __syncthreads(); }
  if (tid==0) atomicAdd(&sums[blockIdx.y], red[0]);
}

// ternarize + write B in MFMA-fragment layout (coalesced B-frag loads)
__global__ __launch_bounds__(256) void wquant4_kernel(
    const float* __restrict__ w0, const float* __restrict__ w1,
    const float* __restrict__ w2, const float* __restrict__ w3,
    int8_t* __restrict__ o0, int8_t* __restrict__ o1,
    int8_t* __restrict__ o2, int8_t* __restrict__ o3,
    const float* __restrict__ sums){
  const float* w; int8_t* o; int n;
  switch(blockIdx.y){
    case 0:  w=w0; o=o0; n=640*640; break;
    case 1:  w=w1; o=o1; n=128*640; break;
    case 2:  w=w2; o=o2; n=128*640; break;
    default: w=w3; o=o3; n=640*640; break;
  }
  float alpha = fmaxf(sums[blockIdx.y]/(float)n, 1e-10f);
  float inva  = 1.0f/alpha;
  int i = blockIdx.x*256 + threadIdx.x;
  if (i < n){
    float t = rintf(w[i]*inva);            // round-half-even matches jnp.round
    t = fminf(1.f, fmaxf(-1.f, t));
    int nr = i/640;
    int kc = i - nr*640;
    o[frag_flat(nr, kc)] = (int8_t)t;
  }
}

// ---------------------------------------------------------------------------
// wave-per-token prep; activations written in A-fragment layout.
__global__ __launch_bounds__(256) void token_prep_kernel(
    const float* __restrict__ x, const float* __restrict__ nw,
    const float* __restrict__ qg, const float* __restrict__ kg, const float* __restrict__ vg,
    int8_t* __restrict__ xqq, int8_t* __restrict__ xqk, int8_t* __restrict__ xqv,
    float* __restrict__ gq, float* __restrict__ gk, float* __restrict__ gv){
  int lane = threadIdx.x & 63;
  int m = blockIdx.x*4 + (threadIdx.x>>6);
  const float* xr = x + (size_t)m*HIDDEN;
  // frag write address: base + koff + j*2048   (k = lane + 64j)
  int abase = ((m>>5)*20480) + ((m&31)<<4)
            + ((lane>>5)<<10) + (((lane>>4)&1)<<9) + (lane&15);
  float xv[10], h[10];
  float ss = 0.f;
  #pragma unroll
  for (int j=0;j<10;j++){ float t = xr[lane + 64*j]; xv[j]=t; ss += t*t; }
  float inv1 = 1.0f/sqrtf(wred_sum(ss)*(1.0f/HIDDEN) + 1e-6f);
  float ss2 = 0.f;
  #pragma unroll
  for (int j=0;j<10;j++){ float t = xv[j]*inv1*nw[lane+64*j]; h[j]=t; ss2 += t*t; }
  float inv2 = 1.0f/sqrtf(wred_sum(ss2)*(1.0f/HIDDEN) + 1e-6f);

  const float* gs[3] = {qg, kg, vg};
  int8_t* outs[3] = {xqq, xqk, xqv};
  float* gams[3] = {gq, gk, gv};
  #pragma unroll
  for (int s=0;s<3;s++){
    const float* g = gs[s];
    float t[10], amax = 0.f;
    #pragma unroll
    for (int j=0;j<10;j++){ float v = h[j]*inv2*g[lane+64*j]; t[j]=v; amax = fmaxf(amax, fabsf(v)); }
    float gamma = fmaxf(wred_max(amax), 1e-10f);
    float sc = 127.0f/gamma;
    int8_t* dst = outs[s] + abase;
    #pragma unroll
    for (int j=0;j<10;j++){
      float v = rintf(t[j]*sc);
      v = fminf(127.f, fmaxf(-128.f, v));
      dst[j*2048] = (int8_t)v;
    }
    if (lane==0) gams[s][m] = gamma;
  }
}

__global__ __launch_bounds__(256) void o_prep_kernel(const _Float16* __restrict__ ao,
    const float* __restrict__ og, int8_t* __restrict__ xqo, float* __restrict__ go){
  int lane = threadIdx.x & 63;
  int m = blockIdx.x*4 + (threadIdx.x>>6);
  const _Float16* xr = ao + (size_t)m*HIDDEN;
  int abase = ((m>>5)*20480) + ((m&31)<<4)
            + ((lane>>5)<<10) + (((lane>>4)&1)<<9) + (lane&15);
  float xv[10];
  float ss = 0.f;
  #pragma unroll
  for (int j=0;j<10;j++){ float t = (float)xr[lane + 64*j]; xv[j]=t; ss += t*t; }
  float inv = 1.0f/sqrtf(wred_sum(ss)*(1.0f/HIDDEN) + 1e-6f);
  float t[10], amax = 0.f;
  #pragma unroll
  for (int j=0;j<10;j++){ float v = xv[j]*inv*og[lane+64*j]; t[j]=v; amax = fmaxf(amax, fabsf(v)); }
  float gamma = fmaxf(wred_max(amax), 1e-10f);
  float sc = 127.0f/gamma;
  int8_t* dst = xqo + abase;
  #pragma unroll
  for (int j=0;j<10;j++){
    float v = rintf(t[j]*sc);
    v = fminf(127.f, fmaxf(-128.f, v));
    dst[j*2048] = (int8_t)v;
  }
  if (lane==0) go[m] = gamma;
}

// ---------------------------------------------------------------------------
// i8 MFMA GEMM core: BOTH A and B in fragment layout -> all loads lane-linear.
__device__ __forceinline__ void gemm_core(
    const int8_t* __restrict__ xq, const int8_t* __restrict__ wqf,
    int m0, int n0, int lane, int16v& acc0, int16v& acc1){
  const int8_t* a0 = xq  + (size_t)(m0>>5)*20480 + (lane<<4);
  const int8_t* b0 = wqf + (size_t)(n0>>5)*20480 + (lane<<4);
  const int8_t* b1 = b0 + 20480;
  #pragma unroll
  for (int kb=0; kb<20; kb++){
    int4v a  = *(const int4v*)(a0 + (kb<<10));
    int4v v0 = *(const int4v*)(b0 + (kb<<10));
    int4v v1 = *(const int4v*)(b1 + (kb<<10));
    acc0 = __builtin_amdgcn_mfma_i32_32x32x32_i8(a, v0, acc0, 0, 0, 0);
    acc1 = __builtin_amdgcn_mfma_i32_32x32x32_i8(a, v1, acc1, 0, 0, 0);
  }
}

// Merged QKV projection: grid (14, 128). bx<10 -> Q (rope, x0.125/ln2),
// bx in {10,11} -> K (rope), bx in {12,13} -> V (transposed store).
__global__ __launch_bounds__(256) void qkv_gemm_kernel(
    const int8_t* __restrict__ xq_q, const float* __restrict__ g_q, const int8_t* __restrict__ wq_q,
    const int8_t* __restrict__ xq_k, const float* __restrict__ g_k, const int8_t* __restrict__ wq_k,
    const int8_t* __restrict__ xq_v, const float* __restrict__ g_v, const int8_t* __restrict__ wq_v,
    const float* __restrict__ sums,
    _Float16* __restrict__ qbuf, _Float16* __restrict__ kbuf, _Float16* __restrict__ vbuf){
  __shared__ _Float16 Tr[4][64][40];
  int bx = blockIdx.x;
  const int8_t *xq, *wq; const float* gam; _Float16* outh;
  int n0, aidx, nheads, mode; float inv_nw, vscale;
  // Q scale folds 1/8 (attn scale) * 1/ln2 (exp2-domain softmax)
  if (bx < 10){ xq=xq_q; wq=wq_q; gam=g_q; outh=qbuf; n0=bx*64;      aidx=0; inv_nw=1.0f/409600.f; nheads=NQH;  mode=1; vscale=0.18033688011110918f; }
  else if (bx < 12){ xq=xq_k; wq=wq_k; gam=g_k; outh=kbuf; n0=(bx-10)*64; aidx=1; inv_nw=1.0f/81920.f; nheads=NKVH; mode=1; vscale=1.0f; }
  else { xq=xq_v; wq=wq_v; gam=g_v; outh=vbuf; n0=(bx-12)*64; aidx=2; inv_nw=1.0f/81920.f; nheads=NKVH; mode=2; vscale=1.0f; }

  int lane = threadIdx.x & 63;
  int w    = threadIdx.x >> 6;
  int m0   = blockIdx.y*128 + w*32;
  int half = lane >> 5, lan5 = lane & 31;

  int16v acc0 = {0}, acc1 = {0};
  gemm_core(xq, wq, m0, n0, lane, acc0, acc1);

  float alpha = fmaxf(sums[aidx]*inv_nw, 1e-10f);
  float fr0 = 0.f, fr1 = 0.f;
  if (mode == 1){
    int d0 = (lan5) & ~1;
    int d1 = (32 + lan5) & ~1;
    fr0 = __expf(-(float)d0*(1.0f/64.0f)*13.122363377404328f);
    fr1 = __expf(-(float)d1*(1.0f/64.0f)*13.122363377404328f);
  }

  #pragma unroll
  for (int reg=0; reg<16; reg++){
    int ml = (reg&3) + 8*(reg>>2) + 4*half;
    int m = m0 + ml;
    float sc = alpha*gam[m]*(1.0f/127.0f);
    float v0 = (float)acc0[reg]*sc;
    float v1 = (float)acc1[reg]*sc;
    if (mode == 1){
      int b = m >> 9, l = m & 511;
      int head = n0 >> 6;
      float p0 = __shfl_xor(v0, 1);
      float p1 = __shfl_xor(v1, 1);
      float sn0, cs0, sn1, cs1;
      __sincosf((float)l*fr0, &sn0, &cs0);
      __sincosf((float)l*fr1, &sn1, &cs1);
      if (lane & 1){ v0 = v0*cs0 + p0*sn0;  v1 = v1*cs1 + p1*sn1; }
      else         { v0 = v0*cs0 - p0*sn0;  v1 = v1*cs1 - p1*sn1; }
      _Float16* dst = outh + ((((size_t)b*nheads + head)*LSEQ + l)<<6);
      dst[lan5]      = (_Float16)(v0*vscale);
      dst[32 + lan5] = (_Float16)(v1*vscale);
    } else {
      Tr[w][lan5][ml]      = (_Float16)v0;
      Tr[w][32 + lan5][ml] = (_Float16)v1;
    }
  }
  if (mode == 2){
    int b = m0 >> 9, l0 = m0 & 511;
    int head = n0 >> 6;
    f16x8 r0 = *(const f16x8*)&Tr[w][lane][0];
    f16x8 r1 = *(const f16x8*)&Tr[w][lane][8];
    f16x8 r2 = *(const f16x8*)&Tr[w][lane][16];
    f16x8 r3 = *(const f16x8*)&Tr[w][lane][24];
    _Float16* dst = outh + (((size_t)b*nheads + head)*HDIM + lane)*LSEQ + l0;
    ((f16x8*)dst)[0] = r0;
    ((f16x8*)dst)[1] = r1;
    ((f16x8*)dst)[2] = r2;
    ((f16x8*)dst)[3] = r3;
  }
}

// O projection + residual (fp32 out)
__global__ __launch_bounds__(256) void out_gemm_kernel(
    const int8_t* __restrict__ xq, const float* __restrict__ gam,
    const int8_t* __restrict__ wq, const float* __restrict__ sums,
    const float* __restrict__ resid, float* __restrict__ outf){
  int lane = threadIdx.x & 63;
  int w    = threadIdx.x >> 6;
  int m0   = blockIdx.y*128 + w*32;
  int n0   = blockIdx.x*64;
  int half = lane >> 5, lan5 = lane & 31;

  int16v acc0 = {0}, acc1 = {0};
  gemm_core(xq, wq, m0, n0, lane, acc0, acc1);

  float alpha = fmaxf(sums[3]*(1.0f/409600.f), 1e-10f);
  #pragma unroll
  for (int reg=0; reg<16; reg++){
    int m = m0 + (reg&3) + 8*(reg>>2) + 4*half;
    float sc = alpha*gam[m]*(1.0f/127.0f);
    size_t ofs = (size_t)m*HIDDEN;
    outf[ofs + n0 + lan5]      = (float)acc0[reg]*sc + resid[ofs + n0 + lan5];
    outf[ofs + n0 + 32 + lan5] = (float)acc1[reg]*sc + resid[ofs + n0 + 32 + lan5];
  }
}

// ---------------------------------------------------------------------------
// Flash attention v6: swapped QK^T (S^T layout, q-row lane-local), softmax
// fully in registers (f32 trees + 2-step 4-lane shfl reductions), P
// re-fragmentation for PV via permlane16/32_swap butterflies (no Ps LDS),
// defer-max rescale (THR=8 in exp2 domain -> P <= 256, f16-safe).
__device__ __forceinline__ int kv_addr(int row, int chunk){  // in halves
  return (row<<6) + (((chunk ^ (row&7)))<<3);
}

// Per-half softmax + P fragment build.
// S[nt][r] = score(key = nt*16 + quad*4 + r, q-row = lane&15).
// Outputs pf0/pf1: PV A-fragments: lane -> P[q-row = lane&15][key = quad*8+j]
// for keys 0-31 / 32-63.
__device__ __forceinline__ void softmax_half(
    const f32x4* S, float& m, float& l, f32x4* O, int quad,
    f16x8& pf0, f16x8& pf1){
  float t0 = fmaxf(fmaxf(S[0][0],S[0][1]), fmaxf(S[0][2],S[0][3]));
  float t1 = fmaxf(fmaxf(S[1][0],S[1][1]), fmaxf(S[1][2],S[1][3]));
  float t2 = fmaxf(fmaxf(S[2][0],S[2][1]), fmaxf(S[2][2],S[2][3]));
  float t3 = fmaxf(fmaxf(S[3][0],S[3][1]), fmaxf(S[3][2],S[3][3]));
  float tmax = fmaxf(fmaxf(t0,t1), fmaxf(t2,t3));
  tmax = fmaxf(tmax, __shfl_xor(tmax, 16));
  tmax = fmaxf(tmax, __shfl_xor(tmax, 32));
  // defer-max: only rescale when some row's max grew by > 8 (log2 domain)
  if (__any(tmax > m + 8.0f)){
    float mnew = fmaxf(m, tmax);
    float af = exp2f(m - mnew);   // 1.0 for stable rows, 0 on first tile
    m = mnew;
    l *= af;
    #pragma unroll
    for (int r=0;r<4;r++){
      float afr = __shfl(af, (quad<<2)+r);   // af for O-row quad*4+r
      O[0][r]*=afr; O[1][r]*=afr; O[2][r]*=afr; O[3][r]*=afr;
    }
  }
  float ps = 0.f;
  uint32_t W[4][2];
  #pragma unroll
  for (int nt=0;nt<4;nt++){
    float p0 = exp2f(S[nt][0]-m);
    float p1 = exp2f(S[nt][1]-m);
    float p2 = exp2f(S[nt][2]-m);
    float p3 = exp2f(S[nt][3]-m);
    ps += (p0+p1)+(p2+p3);
    f16x2 w0 = {(_Float16)p0, (_Float16)p1};
    f16x2 w1 = {(_Float16)p2, (_Float16)p3};
    W[nt][0] = __builtin_bit_cast(uint32_t, w0);
    W[nt][1] = __builtin_bit_cast(uint32_t, w1);
  }
  ps += __shfl_xor(ps, 16);
  ps += __shfl_xor(ps, 32);
  l += ps;
  // 2-stage butterfly: move key bits [3:2] (src quad) -> [4:3] (dest quad).
  // stage 1: swap lane-bit5 <-> slot-bit key[4]   (v_permlane32_swap)
  // stage 2: swap lane-bit4 <-> slot-bit key[3]   (v_permlane16_swap)
  #pragma unroll
  for (int p=0;p<2;p++){
    asm volatile("v_permlane32_swap_b32 %0, %1" : "+v"(W[0][p]), "+v"(W[1][p]));
    asm volatile("v_permlane32_swap_b32 %0, %1" : "+v"(W[2][p]), "+v"(W[3][p]));
    asm volatile("v_permlane16_swap_b32 %0, %1" : "+v"(W[0][p]), "+v"(W[1][p]));
    asm volatile("v_permlane16_swap_b32 %0, %1" : "+v"(W[2][p]), "+v"(W[3][p]));
  }
  union { uint32_t u[4]; f16x8 v; } a, b;
  a.u[0]=W[0][0]; a.u[1]=W[0][1]; a.u[2]=W[1][0]; a.u[3]=W[1][1];
  b.u[0]=W[2][0]; b.u[1]=W[2][1]; b.u[2]=W[3][0]; b.u[3]=W[3][1];
  pf0 = a.v; pf1 = b.v;
}

__global__ __launch_bounds__(256,3) void attn_mfma_kernel(
    const _Float16* __restrict__ q, const _Float16* __restrict__ k,
    const _Float16* __restrict__ vt, _Float16* __restrict__ o){
  __shared__ _Float16 Ks[2][64*64];
  __shared__ _Float16 Vs[2][64*64];
  int tid  = threadIdx.x;
  int wv   = tid >> 6, lane = tid & 63;
  int quad = lane >> 4, c = lane & 15;
  int h = blockIdx.y, b = blockIdx.z;
  int hk = h / GROUPS;
  int qrow0 = blockIdx.x*128 + wv*32;
  (void)wv;

  const _Float16* qb = q + ((size_t)((b*NQH+h)*LSEQ) + qrow0 + c)*HDIM + quad*8;
  f16x8 qa0 = *(const f16x8*)qb;
  f16x8 qa1 = *(const f16x8*)(qb + 32);
  f16x8 qb0 = *(const f16x8*)(qb + 16*HDIM);
  f16x8 qb1 = *(const f16x8*)(qb + 16*HDIM + 32);

  const _Float16* kbase = k  + (size_t)((b*NKVH+hk)*LSEQ)*HDIM;  // [l][d]
  const _Float16* vbase = vt + (size_t)((b*NKVH+hk)*HDIM)*LSEQ;  // [d][l]

  int srow = tid >> 3, schunk = tid & 7;
  const _Float16* kg0 = kbase + (size_t)srow*HDIM      + schunk*8;
  const _Float16* kg1 = kbase + (size_t)(srow+32)*HDIM + schunk*8;
  const _Float16* vg0 = vbase + (size_t)srow*LSEQ      + schunk*8;
  const _Float16* vg1 = vbase + (size_t)(srow+32)*LSEQ + schunk*8;
  int ka0 = kv_addr(srow,    schunk);
  int ka1 = kv_addr(srow+32, schunk);

  {
    f16x8 t0 = *(const f16x8*)kg0;
    f16x8 t1 = *(const f16x8*)kg1;
    f16x8 t2 = *(const f16x8*)vg0;
    f16x8 t3 = *(const f16x8*)vg1;
    *(f16x8*)&Ks[0][ka0] = t0;
    *(f16x8*)&Ks[0][ka1] = t1;
    *(f16x8*)&Vs[0][ka0] = t2;
    *(f16x8*)&Vs[0][ka1] = t3;
  }

  f32x4 O0[4] = {{0,0,0,0},{0,0,0,0},{0,0,0,0},{0,0,0,0}};
  f32x4 O1[4] = {{0,0,0,0},{0,0,0,0},{0,0,0,0},{0,0,0,0}};
  float m0s = -INFINITY, m1s = -INFINITY;
  float l0s = 0.f, l1s = 0.f;
  f16x8 pk0, pk1, pv0, pv1;

  for (int kt=0; kt<8; kt++){
    __syncthreads();
    int cur = kt & 1, nxt = cur ^ 1;
    if (kt < 7){
      pk0 = *(const f16x8*)(kg0 + (size_t)(kt+1)*64*HDIM);
      pk1 = *(const f16x8*)(kg1 + (size_t)(kt+1)*64*HDIM);
      pv0 = *(const f16x8*)(vg0 + (kt+1)*64);
      pv1 = *(const f16x8*)(vg1 + (kt+1)*64);
    }
    // swapped QK^T: S^T[nt] = K(nt-tile) x Q^T -> lane holds q-row c's scores
    f32x4 S0[4], S1[4];
    #pragma unroll
    for (int nt=0; nt<4; nt++){
      int row = (nt<<4) + c;
      f16x8 kf0 = *(const f16x8*)&Ks[cur][kv_addr(row, quad)];
      f16x8 kf1 = *(const f16x8*)&Ks[cur][kv_addr(row, quad+4)];
      f32x4 s = {0,0,0,0};
      s = __builtin_amdgcn_mfma_f32_16x16x32_f16(kf0, qa0, s, 0,0,0);
      s = __builtin_amdgcn_mfma_f32_16x16x32_f16(kf1, qa1, s, 0,0,0);
      S0[nt] = s;
      f32x4 s2 = {0,0,0,0};
      s2 = __builtin_amdgcn_mfma_f32_16x16x32_f16(kf0, qb0, s2, 0,0,0);
      s2 = __builtin_amdgcn_mfma_f32_16x16x32_f16(kf1, qb1, s2, 0,0,0);
      S1[nt] = s2;
    }
    f16x8 pf00, pf01, pf10, pf11;
    softmax_half(S0, m0s, l0s, O0, quad, pf00, pf01);
    softmax_half(S1, m1s, l1s, O1, quad, pf10, pf11);
    #pragma unroll
    for (int nt=0;nt<4;nt++){
      int row = (nt<<4) + c;
      f16x8 vf0 = *(const f16x8*)&Vs[cur][kv_addr(row, quad)];
      f16x8 vf1 = *(const f16x8*)&Vs[cur][kv_addr(row, quad+4)];
      O0[nt] = __builtin_amdgcn_mfma_f32_16x16x32_f16(pf00, vf0, O0[nt], 0,0,0);
      O0[nt] = __builtin_amdgcn_mfma_f32_16x16x32_f16(pf01, vf1, O0[nt], 0,0,0);
      O1[nt] = __builtin_amdgcn_mfma_f32_16x16x32_f16(pf10, vf0, O1[nt], 0,0,0);
      O1[nt] = __builtin_amdgcn_mfma_f32_16x16x32_f16(pf11, vf1, O1[nt], 0,0,0);
    }
    if (kt < 7){
      *(f16x8*)&Ks[nxt][ka0] = pk0;
      *(f16x8*)&Ks[nxt][ka1] = pk1;
      *(f16x8*)&Vs[nxt][ka0] = pv0;
      *(f16x8*)&Vs[nxt][ka1] = pv1;
    }
  }
  #pragma unroll
  for (int r=0;r<4;r++){
    float invl0 = 1.0f/__shfl(l0s, (quad<<2)+r);
    float invl1 = 1.0f/__shfl(l1s, (quad<<2)+r);
    int m0 = (b<<9) + qrow0 + (quad<<2) + r;
    _Float16* d0 = o + (size_t)m0*HIDDEN + (h<<6);
    _Float16* d1 = o + (size_t)(m0+16)*HIDDEN + (h<<6);
    #pragma unroll
    for (int nt=0;nt<4;nt++){
      d0[(nt<<4)+c] = (_Float16)(O0[nt][r]*invl0);
      d1[(nt<<4)+c] = (_Float16)(O1[nt][r]*invl1);
    }
  }
}

// ---------------------------------------------------------------------------
extern "C" void kernel_launch(void* const* d_in, const int* in_sizes, int n_in,
                              void* d_out, int out_size, void* d_ws, size_t ws_size,
                              hipStream_t stream){
  (void)in_sizes; (void)n_in; (void)out_size; (void)ws_size;
  const float* x  = (const float*)d_in[0];
  const float* nw = (const float*)d_in[1];
  const float* qw = (const float*)d_in[2];
  const float* qg = (const float*)d_in[3];
  const float* kw = (const float*)d_in[4];
  const float* kg = (const float*)d_in[5];
  const float* vw = (const float*)d_in[6];
  const float* vg = (const float*)d_in[7];
  const float* ow = (const float*)d_in[8];
  const float* og = (const float*)d_in[9];
  float* out = (float*)d_out;

  char* base = (char*)d_ws;
  size_t off = 0;
  auto alloc = [&](size_t nbytes)->void*{
    off = (off + 255) & ~(size_t)255;
    void* p = base + off;
    off += nbytes;
    return p;
  };
  float*  sums = (float*) alloc(4*sizeof(float));
  int8_t* wq_q = (int8_t*)alloc(640*640);
  int8_t* wq_k = (int8_t*)alloc(128*640);
  int8_t* wq_v = (int8_t*)alloc(128*640);
  int8_t* wq_o = (int8_t*)alloc(640*640);
  int8_t* xq_q = (int8_t*)alloc((size_t)NTOK*HIDDEN);
  int8_t* xq_k = (int8_t*)alloc((size_t)NTOK*HIDDEN);
  int8_t* xq_v = (int8_t*)alloc((size_t)NTOK*HIDDEN);
  int8_t* xq_o = (int8_t*)alloc((size_t)NTOK*HIDDEN);
  float*  g_q  = (float*) alloc((size_t)NTOK*4);
  float*  g_k  = (float*) alloc((size_t)NTOK*4);
  float*  g_v  = (float*) alloc((size_t)NTOK*4);
  float*  g_o  = (float*) alloc((size_t)NTOK*4);
  _Float16* qbuf = (_Float16*)alloc((size_t)BATCH*NQH *LSEQ*HDIM*2);
  _Float16* kbuf = (_Float16*)alloc((size_t)BATCH*NKVH*LSEQ*HDIM*2);
  _Float16* vbuf = (_Float16*)alloc((size_t)BATCH*NKVH*LSEQ*HDIM*2);
  _Float16* abuf = (_Float16*)alloc((size_t)NTOK*HIDDEN*2);

  (void)hipMemsetAsync(sums, 0, 4*sizeof(float), stream);
  absum4_kernel<<<dim3(64,4),256,0,stream>>>(qw, kw, vw, ow, sums);
  wquant4_kernel<<<dim3(1600,4),256,0,stream>>>(qw, kw, vw, ow, wq_q, wq_k, wq_v, wq_o, sums);

  token_prep_kernel<<<NTOK/4,256,0,stream>>>(x, nw, qg, kg, vg, xq_q, xq_k, xq_v, g_q, g_k, g_v);

  qkv_gemm_kernel<<<dim3(14,128),256,0,stream>>>(xq_q, g_q, wq_q,
                                                 xq_k, g_k, wq_k,
                                                 xq_v, g_v, wq_v,
                                                 sums, qbuf, kbuf, vbuf);

  attn_mfma_kernel<<<dim3(4,NQH,BATCH),256,0,stream>>>(qbuf, kbuf, vbuf, abuf);

  o_prep_kernel<<<NTOK/4,256,0,stream>>>(abuf, og, xq_o, g_o);
  out_gemm_kernel<<<dim3(10,128),256,0,stream>>>(xq_o, g_o, wq_o, sums, x, out);
}

// Round 3
// 238.201 us; speedup vs baseline: 1.0940x; 1.0013x over previous
//
#include <hip/hip_runtime.h>
#include <math.h>
#include <stdint.h>

#define HIDDEN 640
#define NTOK   16384   // 32*512
#define LSEQ   512
#define BATCH  32
#define NQH    10
#define NKVH   2
#define HDIM   64
#define GROUPS 5

typedef int      int4v  __attribute__((ext_vector_type(4)));
typedef int      int16v __attribute__((ext_vector_type(16)));
typedef _Float16 f16x8  __attribute__((ext_vector_type(8)));
typedef _Float16 f16x2  __attribute__((ext_vector_type(2)));
typedef float    f32x4  __attribute__((ext_vector_type(4)));

// ---------------------------------------------------------------------------
__device__ __forceinline__ float wred_sum(float v){
  #pragma unroll
  for (int m=1;m<64;m<<=1) v += __shfl_xor(v,m);
  return v;
}
__device__ __forceinline__ float wred_max(float v){
  #pragma unroll
  for (int m=1;m<64;m<<=1) v = fmaxf(v,__shfl_xor(v,m));
  return v;
}

// fragment-layout flat address for an MxK i8 matrix (K=640), used for both
// A (m rows) and B (n rows): lane-linear 16B per (32-row, 32-k) block.
__device__ __forceinline__ int frag_flat(int m, int k){
  return (((m>>5)*20 + (k>>5))<<10) + (((((k>>4)&1)<<5) | (m&31))<<4) + (k&15);
}

// ---------------------------------------------------------------------------
__global__ __launch_bounds__(256) void absum4_kernel(
    const float* __restrict__ w0, const float* __restrict__ w1,
    const float* __restrict__ w2, const float* __restrict__ w3,
    float* __restrict__ sums){
  const float* w; int n;
  switch(blockIdx.y){
    case 0:  w=w0; n=640*640; break;
    case 1:  w=w1; n=128*640; break;
    case 2:  w=w2; n=128*640; break;
    default: w=w3; n=640*640; break;
  }
  __shared__ float red[256];
  int tid = threadIdx.x;
  float s = 0.f;
  for (int i = blockIdx.x*256 + tid; i < n; i += gridDim.x*256) s += fabsf(w[i]);
  red[tid] = s; __syncthreads();
  for (int off=128; off>0; off>>=1){ if (tid<off) red[tid]+=red[tid+off]; __syncthreads(); }
  if (tid==0) atomicAdd(&sums[blockIdx.y], red[0]);
}

// ternarize + write B in MFMA-fragment layout (coalesced B-frag loads)
__global__ __launch_bounds__(256) void wquant4_kernel(
    const float* __restrict__ w0, const float* __restrict__ w1,
    const float* __restrict__ w2, const float* __restrict__ w3,
    int8_t* __restrict__ o0, int8_t* __restrict__ o1,
    int8_t* __restrict__ o2, int8_t* __restrict__ o3,
    const float* __restrict__ sums){
  const float* w; int8_t* o; int n;
  switch(blockIdx.y){
    case 0:  w=w0; o=o0; n=640*640; break;
    case 1:  w=w1; o=o1; n=128*640; break;
    case 2:  w=w2; o=o2; n=128*640; break;
    default: w=w3; o=o3; n=640*640; break;
  }
  float alpha = fmaxf(sums[blockIdx.y]/(float)n, 1e-10f);
  float inva  = 1.0f/alpha;
  int i = blockIdx.x*256 + threadIdx.x;
  if (i < n){
    float t = rintf(w[i]*inva);            // round-half-even matches jnp.round
    t = fminf(1.f, fmaxf(-1.f, t));
    int nr = i/640;
    int kc = i - nr*640;
    o[frag_flat(nr, kc)] = (int8_t)t;
  }
}

// ---------------------------------------------------------------------------
// wave-per-token prep; activations written in A-fragment layout.
__global__ __launch_bounds__(256) void token_prep_kernel(
    const float* __restrict__ x, const float* __restrict__ nw,
    const float* __restrict__ qg, const float* __restrict__ kg, const float* __restrict__ vg,
    int8_t* __restrict__ xqq, int8_t* __restrict__ xqk, int8_t* __restrict__ xqv,
    float* __restrict__ gq, float* __restrict__ gk, float* __restrict__ gv){
  int lane = threadIdx.x & 63;
  int m = blockIdx.x*4 + (threadIdx.x>>6);
  const float* xr = x + (size_t)m*HIDDEN;
  // frag write address: base + koff + j*2048   (k = lane + 64j)
  int abase = ((m>>5)*20480) + ((m&31)<<4)
            + ((lane>>5)<<10) + (((lane>>4)&1)<<9) + (lane&15);
  float xv[10], h[10];
  float ss = 0.f;
  #pragma unroll
  for (int j=0;j<10;j++){ float t = xr[lane + 64*j]; xv[j]=t; ss += t*t; }
  float inv1 = 1.0f/sqrtf(wred_sum(ss)*(1.0f/HIDDEN) + 1e-6f);
  float ss2 = 0.f;
  #pragma unroll
  for (int j=0;j<10;j++){ float t = xv[j]*inv1*nw[lane+64*j]; h[j]=t; ss2 += t*t; }
  float inv2 = 1.0f/sqrtf(wred_sum(ss2)*(1.0f/HIDDEN) + 1e-6f);

  const float* gs[3] = {qg, kg, vg};
  int8_t* outs[3] = {xqq, xqk, xqv};
  float* gams[3] = {gq, gk, gv};
  #pragma unroll
  for (int s=0;s<3;s++){
    const float* g = gs[s];
    float t[10], amax = 0.f;
    #pragma unroll
    for (int j=0;j<10;j++){ float v = h[j]*inv2*g[lane+64*j]; t[j]=v; amax = fmaxf(amax, fabsf(v)); }
    float gamma = fmaxf(wred_max(amax), 1e-10f);
    float sc = 127.0f/gamma;
    int8_t* dst = outs[s] + abase;
    #pragma unroll
    for (int j=0;j<10;j++){
      float v = rintf(t[j]*sc);
      v = fminf(127.f, fmaxf(-128.f, v));
      dst[j*2048] = (int8_t)v;
    }
    if (lane==0) gams[s][m] = gamma;
  }
}

__global__ __launch_bounds__(256) void o_prep_kernel(const _Float16* __restrict__ ao,
    const float* __restrict__ og, int8_t* __restrict__ xqo, float* __restrict__ go){
  int lane = threadIdx.x & 63;
  int m = blockIdx.x*4 + (threadIdx.x>>6);
  const _Float16* xr = ao + (size_t)m*HIDDEN;
  int abase = ((m>>5)*20480) + ((m&31)<<4)
            + ((lane>>5)<<10) + (((lane>>4)&1)<<9) + (lane&15);
  float xv[10];
  float ss = 0.f;
  #pragma unroll
  for (int j=0;j<10;j++){ float t = (float)xr[lane + 64*j]; xv[j]=t; ss += t*t; }
  float inv = 1.0f/sqrtf(wred_sum(ss)*(1.0f/HIDDEN) + 1e-6f);
  float t[10], amax = 0.f;
  #pragma unroll
  for (int j=0;j<10;j++){ float v = xv[j]*inv*og[lane+64*j]; t[j]=v; amax = fmaxf(amax, fabsf(v)); }
  float gamma = fmaxf(wred_max(amax), 1e-10f);
  float sc = 127.0f/gamma;
  int8_t* dst = xqo + abase;
  #pragma unroll
  for (int j=0;j<10;j++){
    float v = rintf(t[j]*sc);
    v = fminf(127.f, fmaxf(-128.f, v));
    dst[j*2048] = (int8_t)v;
  }
  if (lane==0) go[m] = gamma;
}

// ---------------------------------------------------------------------------
// i8 MFMA GEMM core: BOTH A and B in fragment layout -> all loads lane-linear.
__device__ __forceinline__ void gemm_core(
    const int8_t* __restrict__ xq, const int8_t* __restrict__ wqf,
    int m0, int n0, int lane, int16v& acc0, int16v& acc1){
  const int8_t* a0 = xq  + (size_t)(m0>>5)*20480 + (lane<<4);
  const int8_t* b0 = wqf + (size_t)(n0>>5)*20480 + (lane<<4);
  const int8_t* b1 = b0 + 20480;
  #pragma unroll
  for (int kb=0; kb<20; kb++){
    int4v a  = *(const int4v*)(a0 + (kb<<10));
    int4v v0 = *(const int4v*)(b0 + (kb<<10));
    int4v v1 = *(const int4v*)(b1 + (kb<<10));
    acc0 = __builtin_amdgcn_mfma_i32_32x32x32_i8(a, v0, acc0, 0, 0, 0);
    acc1 = __builtin_amdgcn_mfma_i32_32x32x32_i8(a, v1, acc1, 0, 0, 0);
  }
}

// Merged QKV projection: grid (14, 128). bx<10 -> Q (rope, x0.125/ln2),
// bx in {10,11} -> K (rope), bx in {12,13} -> V (transposed store).
__global__ __launch_bounds__(256) void qkv_gemm_kernel(
    const int8_t* __restrict__ xq_q, const float* __restrict__ g_q, const int8_t* __restrict__ wq_q,
    const int8_t* __restrict__ xq_k, const float* __restrict__ g_k, const int8_t* __restrict__ wq_k,
    const int8_t* __restrict__ xq_v, const float* __restrict__ g_v, const int8_t* __restrict__ wq_v,
    const float* __restrict__ sums,
    _Float16* __restrict__ qbuf, _Float16* __restrict__ kbuf, _Float16* __restrict__ vbuf){
  __shared__ _Float16 Tr[4][64][40];
  int bx = blockIdx.x;
  const int8_t *xq, *wq; const float* gam; _Float16* outh;
  int n0, aidx, nheads, mode; float inv_nw, vscale;
  // Q scale folds 1/8 (attn scale) * 1/ln2 (exp2-domain softmax)
  if (bx < 10){ xq=xq_q; wq=wq_q; gam=g_q; outh=qbuf; n0=bx*64;      aidx=0; inv_nw=1.0f/409600.f; nheads=NQH;  mode=1; vscale=0.18033688011110918f; }
  else if (bx < 12){ xq=xq_k; wq=wq_k; gam=g_k; outh=kbuf; n0=(bx-10)*64; aidx=1; inv_nw=1.0f/81920.f; nheads=NKVH; mode=1; vscale=1.0f; }
  else { xq=xq_v; wq=wq_v; gam=g_v; outh=vbuf; n0=(bx-12)*64; aidx=2; inv_nw=1.0f/81920.f; nheads=NKVH; mode=2; vscale=1.0f; }

  int lane = threadIdx.x & 63;
  int w    = threadIdx.x >> 6;
  int m0   = blockIdx.y*128 + w*32;
  int half = lane >> 5, lan5 = lane & 31;

  int16v acc0 = {0}, acc1 = {0};
  gemm_core(xq, wq, m0, n0, lane, acc0, acc1);

  float alpha = fmaxf(sums[aidx]*inv_nw, 1e-10f);
  float fr0 = 0.f, fr1 = 0.f;
  if (mode == 1){
    int d0 = (lan5) & ~1;
    int d1 = (32 + lan5) & ~1;
    fr0 = __expf(-(float)d0*(1.0f/64.0f)*13.122363377404328f);
    fr1 = __expf(-(float)d1*(1.0f/64.0f)*13.122363377404328f);
  }

  #pragma unroll
  for (int reg=0; reg<16; reg++){
    int ml = (reg&3) + 8*(reg>>2) + 4*half;
    int m = m0 + ml;
    float sc = alpha*gam[m]*(1.0f/127.0f);
    float v0 = (float)acc0[reg]*sc;
    float v1 = (float)acc1[reg]*sc;
    if (mode == 1){
      int b = m >> 9, l = m & 511;
      int head = n0 >> 6;
      float p0 = __shfl_xor(v0, 1);
      float p1 = __shfl_xor(v1, 1);
      float sn0, cs0, sn1, cs1;
      __sincosf((float)l*fr0, &sn0, &cs0);
      __sincosf((float)l*fr1, &sn1, &cs1);
      if (lane & 1){ v0 = v0*cs0 + p0*sn0;  v1 = v1*cs1 + p1*sn1; }
      else         { v0 = v0*cs0 - p0*sn0;  v1 = v1*cs1 - p1*sn1; }
      _Float16* dst = outh + ((((size_t)b*nheads + head)*LSEQ + l)<<6);
      dst[lan5]      = (_Float16)(v0*vscale);
      dst[32 + lan5] = (_Float16)(v1*vscale);
    } else {
      Tr[w][lan5][ml]      = (_Float16)v0;
      Tr[w][32 + lan5][ml] = (_Float16)v1;
    }
  }
  if (mode == 2){
    int b = m0 >> 9, l0 = m0 & 511;
    int head = n0 >> 6;
    f16x8 r0 = *(const f16x8*)&Tr[w][lane][0];
    f16x8 r1 = *(const f16x8*)&Tr[w][lane][8];
    f16x8 r2 = *(const f16x8*)&Tr[w][lane][16];
    f16x8 r3 = *(const f16x8*)&Tr[w][lane][24];
    _Float16* dst = outh + (((size_t)b*nheads + head)*HDIM + lane)*LSEQ + l0;
    ((f16x8*)dst)[0] = r0;
    ((f16x8*)dst)[1] = r1;
    ((f16x8*)dst)[2] = r2;
    ((f16x8*)dst)[3] = r3;
  }
}

// O projection + residual (fp32 out)
__global__ __launch_bounds__(256) void out_gemm_kernel(
    const int8_t* __restrict__ xq, const float* __restrict__ gam,
    const int8_t* __restrict__ wq, const float* __restrict__ sums,
    const float* __restrict__ resid, float* __restrict__ outf){
  int lane = threadIdx.x & 63;
  int w    = threadIdx.x >> 6;
  int m0   = blockIdx.y*128 + w*32;
  int n0   = blockIdx.x*64;
  int half = lane >> 5, lan5 = lane & 31;

  int16v acc0 = {0}, acc1 = {0};
  gemm_core(xq, wq, m0, n0, lane, acc0, acc1);

  float alpha = fmaxf(sums[3]*(1.0f/409600.f), 1e-10f);
  #pragma unroll
  for (int reg=0; reg<16; reg++){
    int m = m0 + (reg&3) + 8*(reg>>2) + 4*half;
    float sc = alpha*gam[m]*(1.0f/127.0f);
    size_t ofs = (size_t)m*HIDDEN;
    outf[ofs + n0 + lan5]      = (float)acc0[reg]*sc + resid[ofs + n0 + lan5];
    outf[ofs + n0 + 32 + lan5] = (float)acc1[reg]*sc + resid[ofs + n0 + 32 + lan5];
  }
}

// ---------------------------------------------------------------------------
// Flash attention v7: swapped QK^T with running-max folded into the MFMA
// C-init (S arrives pre-shifted), row-sums l computed on the matrix pipe via
// mfma(P, ones) directly in O-register layout, pkrtz packing, permlane P
// re-fragmentation (no LDS for P), defer-max rescale (THR=8, exp2 domain).
__device__ __forceinline__ int kv_addr(int row, int chunk){  // in halves
  return (row<<6) + (((chunk ^ (row&7)))<<3);
}

// Per-half softmax + P fragment build.
// S[nt][r] = score(key = nt*16 + quad*4 + r, q-row = lane&15) - m_old.
// Outputs pf0/pf1: PV A-fragments: lane -> P[q-row = lane&15][key = quad*8+j]
// for keys 0-31 / 32-63.  lacc (f32x4, O-layout rows quad*4+r) rescaled here;
// caller adds this tile's row-sums via mfma(pf, ones, lacc).
__device__ __forceinline__ void softmax_half(
    const f32x4* S, float& m, f32x4& lacc, f32x4* O, int quad, bool first,
    f16x8& pf0, f16x8& pf1){
  float t0 = fmaxf(fmaxf(S[0][0],S[0][1]), fmaxf(S[0][2],S[0][3]));
  float t1 = fmaxf(fmaxf(S[1][0],S[1][1]), fmaxf(S[1][2],S[1][3]));
  float t2 = fmaxf(fmaxf(S[2][0],S[2][1]), fmaxf(S[2][2],S[2][3]));
  float t3 = fmaxf(fmaxf(S[3][0],S[3][1]), fmaxf(S[3][2],S[3][3]));
  float tmax = fmaxf(fmaxf(t0,t1), fmaxf(t2,t3));
  tmax = fmaxf(tmax, __shfl_xor(tmax, 16));
  tmax = fmaxf(tmax, __shfl_xor(tmax, 32));
  float p[16];
  // defer-max: rescale only when some row's max grew by > 8 (log2 domain).
  // tile 0 forces delta = tmax exactly (handles uniformly-negative rows).
  if (first || __any(tmax > 8.0f)){
    float delta = first ? tmax : fmaxf(tmax, 0.0f);
    m += delta;
    float af = exp2f(-delta);
    #pragma unroll
    for (int r=0;r<4;r++){
      float afr = __shfl(af, (quad<<2)+r);   // af for O-row quad*4+r
      lacc[r] *= afr;
      O[0][r]*=afr; O[1][r]*=afr; O[2][r]*=afr; O[3][r]*=afr;
    }
    #pragma unroll
    for (int nt=0;nt<4;nt++){
      #pragma unroll
      for (int j=0;j<4;j++) p[(nt<<2)+j] = exp2f(S[nt][j] - delta);
    }
  } else {
    #pragma unroll
    for (int nt=0;nt<4;nt++){
      #pragma unroll
      for (int j=0;j<4;j++) p[(nt<<2)+j] = exp2f(S[nt][j]);
    }
  }
  uint32_t W[4][2];
  #pragma unroll
  for (int nt=0;nt<4;nt++){
    W[nt][0] = __builtin_bit_cast(uint32_t,
                 __builtin_amdgcn_cvt_pkrtz(p[(nt<<2)+0], p[(nt<<2)+1]));
    W[nt][1] = __builtin_bit_cast(uint32_t,
                 __builtin_amdgcn_cvt_pkrtz(p[(nt<<2)+2], p[(nt<<2)+3]));
  }
  // 2-stage butterfly: move key bits [3:2] (src quad) -> [4:3] (dest quad).
  // stage 1: swap lane-bit5 <-> slot-bit key[4]   (v_permlane32_swap)
  // stage 2: swap lane-bit4 <-> slot-bit key[3]   (v_permlane16_swap)
  #pragma unroll
  for (int pp=0;pp<2;pp++){
    asm volatile("v_permlane32_swap_b32 %0, %1" : "+v"(W[0][pp]), "+v"(W[1][pp]));
    asm volatile("v_permlane32_swap_b32 %0, %1" : "+v"(W[2][pp]), "+v"(W[3][pp]));
    asm volatile("v_permlane16_swap_b32 %0, %1" : "+v"(W[0][pp]), "+v"(W[1][pp]));
    asm volatile("v_permlane16_swap_b32 %0, %1" : "+v"(W[2][pp]), "+v"(W[3][pp]));
  }
  union { uint32_t u[4]; f16x8 v; } a, b;
  a.u[0]=W[0][0]; a.u[1]=W[0][1]; a.u[2]=W[1][0]; a.u[3]=W[1][1];
  b.u[0]=W[2][0]; b.u[1]=W[2][1]; b.u[2]=W[3][0]; b.u[3]=W[3][1];
  pf0 = a.v; pf1 = b.v;
}

__global__ __launch_bounds__(256,3) void attn_mfma_kernel(
    const _Float16* __restrict__ q, const _Float16* __restrict__ k,
    const _Float16* __restrict__ vt, _Float16* __restrict__ o){
  __shared__ _Float16 Ks[2][64*64];
  __shared__ _Float16 Vs[2][64*64];
  int tid  = threadIdx.x;
  int wv   = tid >> 6, lane = tid & 63;
  int quad = lane >> 4, c = lane & 15;
  int h = blockIdx.y, b = blockIdx.z;
  int hk = h / GROUPS;
  int qrow0 = blockIdx.x*128 + wv*32;

  const _Float16* qb = q + ((size_t)((b*NQH+h)*LSEQ) + qrow0 + c)*HDIM + quad*8;
  f16x8 qa0 = *(const f16x8*)qb;
  f16x8 qa1 = *(const f16x8*)(qb + 32);
  f16x8 qb0 = *(const f16x8*)(qb + 16*HDIM);
  f16x8 qb1 = *(const f16x8*)(qb + 16*HDIM + 32);

  const _Float16* kbase = k  + (size_t)((b*NKVH+hk)*LSEQ)*HDIM;  // [l][d]
  const _Float16* vbase = vt + (size_t)((b*NKVH+hk)*HDIM)*LSEQ;  // [d][l]

  int srow = tid >> 3, schunk = tid & 7;
  const _Float16* kg0 = kbase + (size_t)srow*HDIM      + schunk*8;
  const _Float16* kg1 = kbase + (size_t)(srow+32)*HDIM + schunk*8;
  const _Float16* vg0 = vbase + (size_t)srow*LSEQ      + schunk*8;
  const _Float16* vg1 = vbase + (size_t)(srow+32)*LSEQ + schunk*8;
  int ka0 = kv_addr(srow,    schunk);
  int ka1 = kv_addr(srow+32, schunk);

  {
    f16x8 t0 = *(const f16x8*)kg0;
    f16x8 t1 = *(const f16x8*)kg1;
    f16x8 t2 = *(const f16x8*)vg0;
    f16x8 t3 = *(const f16x8*)vg1;
    *(f16x8*)&Ks[0][ka0] = t0;
    *(f16x8*)&Ks[0][ka1] = t1;
    *(f16x8*)&Vs[0][ka0] = t2;
    *(f16x8*)&Vs[0][ka1] = t3;
  }

  f32x4 O0[4] = {{0,0,0,0},{0,0,0,0},{0,0,0,0},{0,0,0,0}};
  f32x4 O1[4] = {{0,0,0,0},{0,0,0,0},{0,0,0,0},{0,0,0,0}};
  f32x4 lacc0 = {0,0,0,0}, lacc1 = {0,0,0,0};
  float m0s = 0.f, m1s = 0.f;
  const f16x8 ones = {(_Float16)1.f,(_Float16)1.f,(_Float16)1.f,(_Float16)1.f,
                      (_Float16)1.f,(_Float16)1.f,(_Float16)1.f,(_Float16)1.f};
  f16x8 pk0, pk1, pv0, pv1;

  for (int kt=0; kt<8; kt++){
    __syncthreads();
    int cur = kt & 1, nxt = cur ^ 1;
    if (kt < 7){
      pk0 = *(const f16x8*)(kg0 + (size_t)(kt+1)*64*HDIM);
      pk1 = *(const f16x8*)(kg1 + (size_t)(kt+1)*64*HDIM);
      pv0 = *(const f16x8*)(vg0 + (kt+1)*64);
      pv1 = *(const f16x8*)(vg1 + (kt+1)*64);
    }
    // swapped QK^T with C-init = -m: S arrives pre-shifted by the running max
    f32x4 S0[4], S1[4];
    __builtin_amdgcn_s_setprio(1);
    #pragma unroll
    for (int nt=0; nt<4; nt++){
      int row = (nt<<4) + c;
      f16x8 kf0 = *(const f16x8*)&Ks[cur][kv_addr(row, quad)];
      f16x8 kf1 = *(const f16x8*)&Ks[cur][kv_addr(row, quad+4)];
      f32x4 s = {-m0s,-m0s,-m0s,-m0s};
      s = __builtin_amdgcn_mfma_f32_16x16x32_f16(kf0, qa0, s, 0,0,0);
      s = __builtin_amdgcn_mfma_f32_16x16x32_f16(kf1, qa1, s, 0,0,0);
      S0[nt] = s;
      f32x4 s2 = {-m1s,-m1s,-m1s,-m1s};
      s2 = __builtin_amdgcn_mfma_f32_16x16x32_f16(kf0, qb0, s2, 0,0,0);
      s2 = __builtin_amdgcn_mfma_f32_16x16x32_f16(kf1, qb1, s2, 0,0,0);
      S1[nt] = s2;
    }
    __builtin_amdgcn_s_setprio(0);
    f16x8 pf00, pf01, pf10, pf11;
    softmax_half(S0, m0s, lacc0, O0, quad, kt==0, pf00, pf01);
    softmax_half(S1, m1s, lacc1, O1, quad, kt==0, pf10, pf11);
    __builtin_amdgcn_s_setprio(1);
    // row-sums on the matrix pipe, directly in O layout
    lacc0 = __builtin_amdgcn_mfma_f32_16x16x32_f16(pf00, ones, lacc0, 0,0,0);
    lacc0 = __builtin_amdgcn_mfma_f32_16x16x32_f16(pf01, ones, lacc0, 0,0,0);
    lacc1 = __builtin_amdgcn_mfma_f32_16x16x32_f16(pf10, ones, lacc1, 0,0,0);
    lacc1 = __builtin_amdgcn_mfma_f32_16x16x32_f16(pf11, ones, lacc1, 0,0,0);
    #pragma unroll
    for (int nt=0;nt<4;nt++){
      int row = (nt<<4) + c;
      f16x8 vf0 = *(const f16x8*)&Vs[cur][kv_addr(row, quad)];
      f16x8 vf1 = *(const f16x8*)&Vs[cur][kv_addr(row, quad+4)];
      O0[nt] = __builtin_amdgcn_mfma_f32_16x16x32_f16(pf00, vf0, O0[nt], 0,0,0);
      O0[nt] = __builtin_amdgcn_mfma_f32_16x16x32_f16(pf01, vf1, O0[nt], 0,0,0);
      O1[nt] = __builtin_amdgcn_mfma_f32_16x16x32_f16(pf10, vf0, O1[nt], 0,0,0);
      O1[nt] = __builtin_amdgcn_mfma_f32_16x16x32_f16(pf11, vf1, O1[nt], 0,0,0);
    }
    __builtin_amdgcn_s_setprio(0);
    if (kt < 7){
      *(f16x8*)&Ks[nxt][ka0] = pk0;
      *(f16x8*)&Ks[nxt][ka1] = pk1;
      *(f16x8*)&Vs[nxt][ka0] = pv0;
      *(f16x8*)&Vs[nxt][ka1] = pv1;
    }
  }
  #pragma unroll
  for (int r=0;r<4;r++){
    float invl0 = 1.0f/lacc0[r];
    float invl1 = 1.0f/lacc1[r];
    int m0 = (b<<9) + qrow0 + (quad<<2) + r;
    _Float16* d0 = o + (size_t)m0*HIDDEN + (h<<6);
    _Float16* d1 = o + (size_t)(m0+16)*HIDDEN + (h<<6);
    #pragma unroll
    for (int nt=0;nt<4;nt++){
      d0[(nt<<4)+c] = (_Float16)(O0[nt][r]*invl0);
      d1[(nt<<4)+c] = (_Float16)(O1[nt][r]*invl1);
    }
  }
}

// ---------------------------------------------------------------------------
extern "C" void kernel_launch(void* const* d_in, const int* in_sizes, int n_in,
                              void* d_out, int out_size, void* d_ws, size_t ws_size,
                              hipStream_t stream){
  (void)in_sizes; (void)n_in; (void)out_size; (void)ws_size;
  const float* x  = (const float*)d_in[0];
  const float* nw = (const float*)d_in[1];
  const float* qw = (const float*)d_in[2];
  const float* qg = (const float*)d_in[3];
  const float* kw = (const float*)d_in[4];
  const float* kg = (const float*)d_in[5];
  const float* vw = (const float*)d_in[6];
  const float* vg = (const float*)d_in[7];
  const float* ow = (const float*)d_in[8];
  const float* og = (const float*)d_in[9];
  float* out = (float*)d_out;

  char* base = (char*)d_ws;
  size_t off = 0;
  auto alloc = [&](size_t nbytes)->void*{
    off = (off + 255) & ~(size_t)255;
    void* p = base + off;
    off += nbytes;
    return p;
  };
  float*  sums = (float*) alloc(4*sizeof(float));
  int8_t* wq_q = (int8_t*)alloc(640*640);
  int8_t* wq_k = (int8_t*)alloc(128*640);
  int8_t* wq_v = (int8_t*)alloc(128*640);
  int8_t* wq_o = (int8_t*)alloc(640*640);
  int8_t* xq_q = (int8_t*)alloc((size_t)NTOK*HIDDEN);
  int8_t* xq_k = (int8_t*)alloc((size_t)NTOK*HIDDEN);
  int8_t* xq_v = (int8_t*)alloc((size_t)NTOK*HIDDEN);
  int8_t* xq_o = (int8_t*)alloc((size_t)NTOK*HIDDEN);
  float*  g_q  = (float*) alloc((size_t)NTOK*4);
  float*  g_k  = (float*) alloc((size_t)NTOK*4);
  float*  g_v  = (float*) alloc((size_t)NTOK*4);
  float*  g_o  = (float*) alloc((size_t)NTOK*4);
  _Float16* qbuf = (_Float16*)alloc((size_t)BATCH*NQH *LSEQ*HDIM*2);
  _Float16* kbuf = (_Float16*)alloc((size_t)BATCH*NKVH*LSEQ*HDIM*2);
  _Float16* vbuf = (_Float16*)alloc((size_t)BATCH*NKVH*LSEQ*HDIM*2);
  _Float16* abuf = (_Float16*)alloc((size_t)NTOK*HIDDEN*2);

  (void)hipMemsetAsync(sums, 0, 4*sizeof(float), stream);
  absum4_kernel<<<dim3(64,4),256,0,stream>>>(qw, kw, vw, ow, sums);
  wquant4_kernel<<<dim3(1600,4),256,0,stream>>>(qw, kw, vw, ow, wq_q, wq_k, wq_v, wq_o, sums);

  token_prep_kernel<<<NTOK/4,256,0,stream>>>(x, nw, qg, kg, vg, xq_q, xq_k, xq_v, g_q, g_k, g_v);

  qkv_gemm_kernel<<<dim3(14,128),256,0,stream>>>(xq_q, g_q, wq_q,
                                                 xq_k, g_k, wq_k,
                                                 xq_v, g_v, wq_v,
                                                 sums, qbuf, kbuf, vbuf);

  attn_mfma_kernel<<<dim3(4,NQH,BATCH),256,0,stream>>>(qbuf, kbuf, vbuf, abuf);

  o_prep_kernel<<<NTOK/4,256,0,stream>>>(abuf, og, xq_o, g_o);
  out_gemm_kernel<<<dim3(10,128),256,0,stream>>>(xq_o, g_o, wq_o, sums, x, out);
}